// Round 3
// baseline (956.542 us; speedup 1.0000x reference)
//
#include <hip/hip_runtime.h>

#define B_ 256
#define T_ 2048
#define H_ 64

typedef float f32x2 __attribute__((ext_vector_type(2)));
typedef float f32x4 __attribute__((ext_vector_type(4)));

// Packed fp32 FMA/ADD (gfx90a+ VOP3P). Forces VGPR residency of operands and
// halves VALU issue count vs scalarized float2 math.
__device__ __forceinline__ void pk_fma(f32x2& d, f32x2 a, f32x2 b) {
    asm("v_pk_fma_f32 %0, %1, %2, %0" : "+v"(d) : "v"(a), "v"(b));
}
__device__ __forceinline__ f32x2 pk_add(f32x2 a, f32x2 b) {
    f32x2 d;
    asm("v_pk_add_f32 %0, %1, %2" : "=v"(d) : "v"(a), "v"(b));
    return d;
}

__device__ __forceinline__ float fast_sigmoid(float v) {
    float e = __builtin_amdgcn_exp2f(-1.4426950408889634f * v);
    return __builtin_amdgcn_rcpf(1.0f + e);
}

__device__ __forceinline__ float fast_tanh(float v) {
    float e = __builtin_amdgcn_exp2f(2.8853900817779268f * v);
    return fmaf(-2.0f, __builtin_amdgcn_rcpf(1.0f + e), 1.0f);
}

__device__ __forceinline__ float readlane_f(float v, int idx) {
    return __builtin_bit_cast(float,
        __builtin_amdgcn_readlane(__builtin_bit_cast(int, v), idx));
}

// One wave per batch row. Lane j owns hidden channel j, computes all 3 gate
// rows (r,z,n) with W_hh rows resident in 192 VGPRs (asm pk_fma pins them).
// h lives in a 64-float LDS buffer: 1 ds_write + 32 broadcast ds_read_b64
// per step, zero barriers. x distributed via readlane from a per-64-step
// coalesced load. Total time = 2048 * step_latency; everything below is
// about shortening the step critical path.
__global__ __launch_bounds__(64, 1)
void gru_kernel(const float* __restrict__ x,
                const float* __restrict__ W_ih,
                const float* __restrict__ W_hh,
                const float* __restrict__ b_ih,
                const float* __restrict__ b_hh,
                float* __restrict__ out)
{
    __shared__ float shh[H_];

    const int lane = threadIdx.x;
    const int b    = blockIdx.x;

    // ---- preload W_hh rows {lane, 64+lane, 128+lane} into f32x2 regs ----
    f32x2 wr[32], wz[32], wn[32];
    {
        const f32x4* pr = (const f32x4*)(W_hh + (size_t)lane * H_);
        const f32x4* pz = (const f32x4*)(W_hh + (size_t)(64 + lane) * H_);
        const f32x4* pn = (const f32x4*)(W_hh + (size_t)(128 + lane) * H_);
        #pragma unroll
        for (int q = 0; q < 16; ++q) {
            f32x4 vr = pr[q], vz = pz[q], vn = pn[q];
            wr[2*q] = f32x2{vr.x, vr.y}; wr[2*q+1] = f32x2{vr.z, vr.w};
            wz[2*q] = f32x2{vz.x, vz.y}; wz[2*q+1] = f32x2{vz.z, vz.w};
            wn[2*q] = f32x2{vn.x, vn.y}; wn[2*q+1] = f32x2{vn.z, vn.w};
        }
    }

    const float wihr = W_ih[lane];
    const float wihz = W_ih[64 + lane];
    const float wihn = W_ih[128 + lane];
    const float br   = b_ih[lane]      + b_hh[lane];
    const float bz   = b_ih[64 + lane] + b_hh[64 + lane];
    const float bhn  = b_hh[128 + lane];
    const float bin  = b_ih[128 + lane];

    const float* __restrict__ xrow = x + (size_t)b * T_;
    float* __restrict__ orow = out + (size_t)b * T_;

    shh[lane] = 0.0f;          // h0 = 0 (single wave: LDS pipe is in-order)

    float h_own = 0.0f;
    float xa = xrow[lane];     // current 64-step block of x
    float xb = 0.0f;

    for (int tb = 0; tb < T_ / 64; ++tb) {
        if (tb < T_ / 64 - 1) xb = xrow[(tb + 1) * 64 + lane];  // prefetch
        float oval = 0.0f;

        #pragma unroll 8
        for (int t2 = 0; t2 < 64; ++t2) {
            const float xt = readlane_f(xa, t2);
            // x-side scalars early: fill the LDS read-latency window
            const float xpr = fmaf(xt, wihr, br);
            const float xpz = fmaf(xt, wihz, bz);
            const float xpn = fmaf(xt, wihn, bin);

            f32x2 ar0 = {0.f,0.f}, ar1 = {0.f,0.f};
            f32x2 az0 = {0.f,0.f}, az1 = {0.f,0.f};
            f32x2 an0 = {0.f,0.f}, an1 = {0.f,0.f};
            const f32x2* hp = (const f32x2*)shh;
            #pragma unroll
            for (int q = 0; q < 16; ++q) {
                f32x2 h0 = hp[2*q], h1 = hp[2*q+1];   // broadcast reads
                pk_fma(ar0, wr[2*q], h0);  pk_fma(ar1, wr[2*q+1], h1);
                pk_fma(az0, wz[2*q], h0);  pk_fma(az1, wz[2*q+1], h1);
                pk_fma(an0, wn[2*q], h0);  pk_fma(an1, wn[2*q+1], h1);
            }
            f32x2 sr2 = pk_add(ar0, ar1);
            f32x2 sz2 = pk_add(az0, az1);
            f32x2 sn2 = pk_add(an0, an1);

            float r  = fast_sigmoid(sr2.x + sr2.y + xpr);
            float z  = fast_sigmoid(sz2.x + sz2.y + xpz);
            float hn = sn2.x + sn2.y + bhn;
            float n  = fast_tanh(fmaf(r, hn, xpn));
            float h_new = n + z * (h_own - n);   // (1-z)*n + z*h
            h_own = h_new;

            shh[lane] = h_new;                   // publish for next step

            float h63 = readlane_f(h_new, 63);
            oval = (t2 == lane) ? h63 : oval;    // latch out[t]
        }

        orow[tb * 64 + lane] = oval;             // coalesced 256B store
        xa = xb;
    }
}

extern "C" void kernel_launch(void* const* d_in, const int* in_sizes, int n_in,
                              void* d_out, int out_size, void* d_ws, size_t ws_size,
                              hipStream_t stream) {
    const float* x    = (const float*)d_in[0];
    const float* W_ih = (const float*)d_in[1];
    const float* W_hh = (const float*)d_in[2];
    const float* b_ih = (const float*)d_in[3];
    const float* b_hh = (const float*)d_in[4];
    float* out = (float*)d_out;

    dim3 grid(B_), block(64);
    gru_kernel<<<grid, block, 0, stream>>>(x, W_ih, W_hh, b_ih, b_hh, out);
}